// Round 1
// baseline (1012.365 us; speedup 1.0000x reference)
//
#include <hip/hip_runtime.h>
#include <hip/hip_bf16.h>
#include <math.h>

// ---------------------------------------------------------------------------
// RESKnorm GCN pipeline:
//   h = relu(gcn(x, W0,b0))
//   h = gn(relu(gcn(h,W1,b1)),g1,beta1) + h
//   h = gn(relu(gcn(h,W2,b2)),g2,beta2) + h
//   out = log_softmax(gcn(h,W3,b3))
// gcn(x,W,b) = segment_sum((x@W+b)[src] * Mtgt, tgt)
// N=50000, E=800000, NFEAT=128, NHID=64, NCLASS=40, GROUPS=32 (2 ch/group)
// ---------------------------------------------------------------------------

#define EPS 1e-5f

// S = X @ W + b   (X: [n,K], W: [K,COLS], S: [n,COLS])
template <int K, int COLS>
__global__ void lin_kernel(const float* __restrict__ X,
                           const float* __restrict__ W,
                           const float* __restrict__ B,
                           float* __restrict__ S, int n) {
    __shared__ float Wl[K * COLS];
    __shared__ float Bl[COLS];
    for (int i = threadIdx.x; i < K * COLS; i += blockDim.x) Wl[i] = W[i];
    for (int i = threadIdx.x; i < COLS; i += blockDim.x) Bl[i] = B[i];
    __syncthreads();
    int idx = blockIdx.x * blockDim.x + threadIdx.x;
    int total = n * COLS;
    if (idx >= total) return;
    int row = idx / COLS;
    int col = idx - row * COLS;
    const float* xr = X + (long)row * K;
    float acc = Bl[col];
#pragma unroll 8
    for (int k = 0; k < K; ++k) acc = fmaf(xr[k], Wl[k * COLS + col], acc);
    S[idx] = acc;
}

// agg[tgt[e]] += S[src[e]] * mv[e], one thread per (edge, feature)
template <int F>
__global__ void scatter_kernel(const float* __restrict__ S,
                               const int* __restrict__ src,
                               const int* __restrict__ tgt,
                               const float* __restrict__ mv,
                               float* __restrict__ agg, int E) {
    int idx = blockIdx.x * blockDim.x + threadIdx.x;
    int total = E * F;
    if (idx >= total) return;
    int e = idx / F;
    int f = idx - e * F;
    int s = src[e];
    int t = tgt[e];
    float v = S[(long)s * F + f] * mv[e];
    atomicAdd(&agg[(long)t * F + f], v);
}

__global__ void relu_kernel(const float* __restrict__ A, float* __restrict__ H,
                            int total) {
    int i = blockIdx.x * blockDim.x + threadIdx.x;
    if (i >= total) return;
    H[i] = fmaxf(A[i], 0.0f);
}

// h = groupnorm(relu(agg)) + h     (64 channels, 32 groups -> 2 ch/group)
// one thread per (row, group): handles a float2 channel pair
__global__ void post_kernel(const float* __restrict__ A,
                            const float* __restrict__ gamma,
                            const float* __restrict__ beta,
                            float* __restrict__ H, int n) {
    int idx = blockIdx.x * blockDim.x + threadIdx.x;
    int total = n * 32;
    if (idx >= total) return;
    int row = idx >> 5;
    int g = idx & 31;
    long off = (long)row * 64 + 2 * g;
    float a0 = fmaxf(A[off], 0.0f);
    float a1 = fmaxf(A[off + 1], 0.0f);
    float mu = 0.5f * (a0 + a1);
    float d0 = a0 - mu;
    float d1 = a1 - mu;
    float var = 0.5f * (d0 * d0 + d1 * d1);
    float rs = rsqrtf(var + EPS);
    float n0 = d0 * rs;
    float n1 = d1 * rs;
    float ga0 = gamma[2 * g], ga1 = gamma[2 * g + 1];
    float be0 = beta[2 * g], be1 = beta[2 * g + 1];
    H[off] = n0 * ga0 + be0 + H[off];
    H[off + 1] = n1 * ga1 + be1 + H[off + 1];
}

// out = log_softmax(A) per row of 40
__global__ void logsoftmax_kernel(const float* __restrict__ A,
                                  float* __restrict__ out, int n) {
    int row = blockIdx.x * blockDim.x + threadIdx.x;
    if (row >= n) return;
    const float* a = A + (long)row * 40;
    float v[40];
    float m = -INFINITY;
#pragma unroll
    for (int i = 0; i < 40; ++i) {
        v[i] = a[i];
        m = fmaxf(m, v[i]);
    }
    float s = 0.0f;
#pragma unroll
    for (int i = 0; i < 40; ++i) s += expf(v[i] - m);
    float l = m + logf(s);
    float* o = out + (long)row * 40;
#pragma unroll
    for (int i = 0; i < 40; ++i) o[i] = v[i] - l;
}

extern "C" void kernel_launch(void* const* d_in, const int* in_sizes, int n_in,
                              void* d_out, int out_size, void* d_ws,
                              size_t ws_size, hipStream_t stream) {
    const float* x = (const float*)d_in[0];
    const int* src = (const int*)d_in[1];
    const int* tgt = (const int*)d_in[2];
    const float* mv = (const float*)d_in[3];
    const float* W0 = (const float*)d_in[4];
    const float* b0 = (const float*)d_in[5];
    const float* W1 = (const float*)d_in[6];
    const float* b1 = (const float*)d_in[7];
    const float* W2 = (const float*)d_in[8];
    const float* b2 = (const float*)d_in[9];
    const float* W3 = (const float*)d_in[10];
    const float* b3 = (const float*)d_in[11];
    const float* g1 = (const float*)d_in[12];
    const float* beta1 = (const float*)d_in[13];
    const float* g2 = (const float*)d_in[14];
    const float* beta2 = (const float*)d_in[15];

    const int N = in_sizes[0] / 128;
    const int E = in_sizes[1];

    float* buf_s = (float*)d_ws;               // [N,64] linear output
    float* buf_h = buf_s + (size_t)N * 64;     // [N,64] current h / residual
    float* buf_a = buf_h + (size_t)N * 64;     // [N,64] aggregation target

    const int BLK = 256;
    auto grid = [](long total, int blk) { return (int)((total + blk - 1) / blk); };

    // ---- layer 0: h = relu(gcn(x, W0, b0)) ----
    lin_kernel<128, 64><<<grid((long)N * 64, BLK), BLK, 0, stream>>>(x, W0, b0, buf_s, N);
    hipMemsetAsync(buf_a, 0, (size_t)N * 64 * sizeof(float), stream);
    scatter_kernel<64><<<grid((long)E * 64, BLK), BLK, 0, stream>>>(buf_s, src, tgt, mv, buf_a, E);
    relu_kernel<<<grid((long)N * 64, BLK), BLK, 0, stream>>>(buf_a, buf_h, N * 64);

    // ---- layer 1: h = gn(relu(gcn(h,W1,b1)),g1,beta1) + h ----
    lin_kernel<64, 64><<<grid((long)N * 64, BLK), BLK, 0, stream>>>(buf_h, W1, b1, buf_s, N);
    hipMemsetAsync(buf_a, 0, (size_t)N * 64 * sizeof(float), stream);
    scatter_kernel<64><<<grid((long)E * 64, BLK), BLK, 0, stream>>>(buf_s, src, tgt, mv, buf_a, E);
    post_kernel<<<grid((long)N * 32, BLK), BLK, 0, stream>>>(buf_a, g1, beta1, buf_h, N);

    // ---- layer 2: h = gn(relu(gcn(h,W2,b2)),g2,beta2) + h ----
    lin_kernel<64, 64><<<grid((long)N * 64, BLK), BLK, 0, stream>>>(buf_h, W2, b2, buf_s, N);
    hipMemsetAsync(buf_a, 0, (size_t)N * 64 * sizeof(float), stream);
    scatter_kernel<64><<<grid((long)E * 64, BLK), BLK, 0, stream>>>(buf_s, src, tgt, mv, buf_a, E);
    post_kernel<<<grid((long)N * 32, BLK), BLK, 0, stream>>>(buf_a, g2, beta2, buf_h, N);

    // ---- layer 3: out = log_softmax(gcn(h, W3, b3)) ----
    lin_kernel<64, 40><<<grid((long)N * 40, BLK), BLK, 0, stream>>>(buf_h, W3, b3, buf_s, N);
    hipMemsetAsync(buf_a, 0, (size_t)N * 40 * sizeof(float), stream);
    scatter_kernel<40><<<grid((long)E * 40, BLK), BLK, 0, stream>>>(buf_s, src, tgt, mv, buf_a, E);
    logsoftmax_kernel<<<grid(N, BLK), BLK, 0, stream>>>(buf_a, (float*)d_out, N);
}

// Round 2
// 578.333 us; speedup vs baseline: 1.7505x; 1.7505x over previous
//
#include <hip/hip_runtime.h>
#include <hip/hip_bf16.h>
#include <math.h>

// ---------------------------------------------------------------------------
// RESKnorm GCN, CSR-based (no float atomics):
//   per call: build CSR of edges grouped by tgt (histogram+scan+fill), then
//   each layer: S = X@W+b (lin), then one-wave-per-node aggregation with
//   fused epilogue (relu / relu+GN+residual / log_softmax).
// N=50000, E=800000, NFEAT=128, NHID=64, NCLASS=40, GROUPS=32 (2 ch/group)
// ---------------------------------------------------------------------------

#define EPS 1e-5f

// ---------------- CSR build ----------------
__global__ void count_kernel(const int* __restrict__ tgt, int* __restrict__ cnt,
                             int E) {
    int e = blockIdx.x * blockDim.x + threadIdx.x;
    if (e < E) atomicAdd(&cnt[tgt[e]], 1);
}

// single-block exclusive scan: cnt[0..n) -> rowptr[0..n], cursor = rowptr copy
__global__ void scan_kernel(const int* __restrict__ cnt, int* __restrict__ rowptr,
                            int* __restrict__ cursor, int n) {
    __shared__ int partial[1024];
    int tid = threadIdx.x;
    int per = (n + 1023) / 1024;
    int beg = tid * per;
    int end = min(beg + per, n);
    int sum = 0;
    for (int i = beg; i < end; ++i) sum += cnt[i];
    partial[tid] = sum;
    __syncthreads();
    for (int off = 1; off < 1024; off <<= 1) {
        int v = (tid >= off) ? partial[tid - off] : 0;
        __syncthreads();
        partial[tid] += v;
        __syncthreads();
    }
    int base = (tid == 0) ? 0 : partial[tid - 1];
    for (int i = beg; i < end; ++i) {
        rowptr[i] = base;
        cursor[i] = base;
        base += cnt[i];
    }
    if (tid == 1023) rowptr[n] = partial[1023];
}

__global__ void fill_kernel(const int* __restrict__ src, const int* __restrict__ tgt,
                            const float* __restrict__ mv, int* __restrict__ cursor,
                            int* __restrict__ colidx, float* __restrict__ wv, int E) {
    int e = blockIdx.x * blockDim.x + threadIdx.x;
    if (e >= E) return;
    int pos = atomicAdd(&cursor[tgt[e]], 1);
    colidx[pos] = src[e];
    wv[pos] = mv[e];
}

// ---------------- S = X @ W + b ----------------
// one thread computes 4 consecutive output cols; W tile in LDS as float4
template <int K, int COLS>
__global__ void lin_kernel(const float* __restrict__ X, const float* __restrict__ W,
                           const float* __restrict__ B, float* __restrict__ S,
                           int n) {
    constexpr int C4 = COLS / 4;
    __shared__ float4 Wl[K * C4];
    __shared__ float Bl[COLS];
    for (int i = threadIdx.x; i < K * C4; i += blockDim.x)
        Wl[i] = ((const float4*)W)[i];
    for (int i = threadIdx.x; i < COLS; i += blockDim.x) Bl[i] = B[i];
    __syncthreads();
    int idx = blockIdx.x * blockDim.x + threadIdx.x;
    int total = n * C4;
    if (idx >= total) return;
    int row = idx / C4;
    int c4 = idx - row * C4;
    const float* xr = X + (long)row * K;
    float4 acc;
    acc.x = Bl[4 * c4 + 0];
    acc.y = Bl[4 * c4 + 1];
    acc.z = Bl[4 * c4 + 2];
    acc.w = Bl[4 * c4 + 3];
#pragma unroll 4
    for (int k = 0; k < K; ++k) {
        float xv = xr[k];
        float4 w = Wl[k * C4 + c4];
        acc.x = fmaf(xv, w.x, acc.x);
        acc.y = fmaf(xv, w.y, acc.y);
        acc.z = fmaf(xv, w.z, acc.z);
        acc.w = fmaf(xv, w.w, acc.w);
    }
    ((float4*)S)[idx] = acc;
}

// ---------------- aggregation: one wave per node, lane = channel ----------
// layer 0 epilogue: relu
__global__ void agg_relu_kernel(const float* __restrict__ S,
                                const int* __restrict__ rowptr,
                                const int* __restrict__ colidx,
                                const float* __restrict__ wv,
                                float* __restrict__ H, int n) {
    int wid = (blockIdx.x * blockDim.x + threadIdx.x) >> 6;
    int lane = threadIdx.x & 63;
    if (wid >= n) return;
    int beg = rowptr[wid], end = rowptr[wid + 1];
    float acc0 = 0.f, acc1 = 0.f;
    int j = beg;
    for (; j + 1 < end; j += 2) {
        int s0 = colidx[j], s1 = colidx[j + 1];
        float w0 = wv[j], w1 = wv[j + 1];
        acc0 = fmaf(S[(long)s0 * 64 + lane], w0, acc0);
        acc1 = fmaf(S[(long)s1 * 64 + lane], w1, acc1);
    }
    if (j < end) acc0 = fmaf(S[(long)colidx[j] * 64 + lane], wv[j], acc0);
    H[(long)wid * 64 + lane] = fmaxf(acc0 + acc1, 0.f);
}

// layers 1-2 epilogue: relu + groupnorm(2ch/group, closed form) + residual
// in-place on H (each thread reads/writes only its own element)
__global__ void agg_gn_kernel(const float* __restrict__ S,
                              const int* __restrict__ rowptr,
                              const int* __restrict__ colidx,
                              const float* __restrict__ wv,
                              const float* __restrict__ gamma,
                              const float* __restrict__ beta,
                              float* __restrict__ H, int n) {
    int wid = (blockIdx.x * blockDim.x + threadIdx.x) >> 6;
    int lane = threadIdx.x & 63;
    if (wid >= n) return;
    int beg = rowptr[wid], end = rowptr[wid + 1];
    float acc0 = 0.f, acc1 = 0.f;
    int j = beg;
    for (; j + 1 < end; j += 2) {
        int s0 = colidx[j], s1 = colidx[j + 1];
        float w0 = wv[j], w1 = wv[j + 1];
        acc0 = fmaf(S[(long)s0 * 64 + lane], w0, acc0);
        acc1 = fmaf(S[(long)s1 * 64 + lane], w1, acc1);
    }
    if (j < end) acc0 = fmaf(S[(long)colidx[j] * 64 + lane], wv[j], acc0);
    float a = fmaxf(acc0 + acc1, 0.f);
    float b = __shfl_xor(a, 1);       // partner channel within the 2-ch group
    float d = 0.5f * (a - b);         // a - mu ; var = d*d
    float rs = rsqrtf(d * d + EPS);
    long off = (long)wid * 64 + lane;
    H[off] = d * rs * gamma[lane] + beta[lane] + H[off];
}

// layer 3 epilogue: log_softmax over 40 classes (lanes 0..39 active)
__global__ void agg_lsm_kernel(const float* __restrict__ S,
                               const int* __restrict__ rowptr,
                               const int* __restrict__ colidx,
                               const float* __restrict__ wv,
                               float* __restrict__ out, int n) {
    int wid = (blockIdx.x * blockDim.x + threadIdx.x) >> 6;
    int lane = threadIdx.x & 63;
    if (wid >= n) return;
    int beg = rowptr[wid], end = rowptr[wid + 1];
    bool act = lane < 40;
    float acc0 = 0.f, acc1 = 0.f;
    int j = beg;
    for (; j + 1 < end; j += 2) {
        int s0 = colidx[j], s1 = colidx[j + 1];
        float w0 = wv[j], w1 = wv[j + 1];
        if (act) {
            acc0 = fmaf(S[(long)s0 * 40 + lane], w0, acc0);
            acc1 = fmaf(S[(long)s1 * 40 + lane], w1, acc1);
        }
    }
    if (j < end && act) acc0 = fmaf(S[(long)colidx[j] * 40 + lane], wv[j], acc0);
    float v = acc0 + acc1;
    float m = act ? v : -INFINITY;
#pragma unroll
    for (int off = 32; off; off >>= 1) m = fmaxf(m, __shfl_xor(m, off));
    float ex = act ? expf(v - m) : 0.f;
#pragma unroll
    for (int off = 32; off; off >>= 1) ex += __shfl_xor(ex, off);
    float l = m + logf(ex);
    if (act) out[(long)wid * 40 + lane] = v - l;
}

extern "C" void kernel_launch(void* const* d_in, const int* in_sizes, int n_in,
                              void* d_out, int out_size, void* d_ws,
                              size_t ws_size, hipStream_t stream) {
    const float* x = (const float*)d_in[0];
    const int* src = (const int*)d_in[1];
    const int* tgt = (const int*)d_in[2];
    const float* mv = (const float*)d_in[3];
    const float* W0 = (const float*)d_in[4];
    const float* b0 = (const float*)d_in[5];
    const float* W1 = (const float*)d_in[6];
    const float* b1 = (const float*)d_in[7];
    const float* W2 = (const float*)d_in[8];
    const float* b2 = (const float*)d_in[9];
    const float* W3 = (const float*)d_in[10];
    const float* b3 = (const float*)d_in[11];
    const float* g1 = (const float*)d_in[12];
    const float* beta1 = (const float*)d_in[13];
    const float* g2 = (const float*)d_in[14];
    const float* beta2 = (const float*)d_in[15];

    const int N = in_sizes[0] / 128;
    const int E = in_sizes[1];

    float* buf_s = (float*)d_ws;               // [N,64] linear output
    float* buf_h = buf_s + (size_t)N * 64;     // [N,64] h / residual (in-place)
    int* rowptr = (int*)(buf_h + (size_t)N * 64);  // [N+1]
    int* cursor = rowptr + (N + 1);            // [N]
    int* cnt = cursor + N;                     // [N]
    int* colidx = cnt + N;                     // [E]
    float* wv = (float*)(colidx + E);          // [E]

    const int BLK = 256;
    auto grid = [](long total, int blk) { return (int)((total + blk - 1) / blk); };

    // ---- CSR build (once per call; reused by all 4 layers) ----
    hipMemsetAsync(cnt, 0, (size_t)N * sizeof(int), stream);
    count_kernel<<<grid(E, BLK), BLK, 0, stream>>>(tgt, cnt, E);
    scan_kernel<<<1, 1024, 0, stream>>>(cnt, rowptr, cursor, N);
    fill_kernel<<<grid(E, BLK), BLK, 0, stream>>>(src, tgt, mv, cursor, colidx, wv, E);

    const int aggBlocks = grid((long)N * 64, BLK);  // 4 waves (nodes) per block

    // ---- layer 0: h = relu(gcn(x, W0, b0)) ----
    lin_kernel<128, 64><<<grid((long)N * 16, BLK), BLK, 0, stream>>>(x, W0, b0, buf_s, N);
    agg_relu_kernel<<<aggBlocks, BLK, 0, stream>>>(buf_s, rowptr, colidx, wv, buf_h, N);

    // ---- layer 1 ----
    lin_kernel<64, 64><<<grid((long)N * 16, BLK), BLK, 0, stream>>>(buf_h, W1, b1, buf_s, N);
    agg_gn_kernel<<<aggBlocks, BLK, 0, stream>>>(buf_s, rowptr, colidx, wv, g1, beta1, buf_h, N);

    // ---- layer 2 ----
    lin_kernel<64, 64><<<grid((long)N * 16, BLK), BLK, 0, stream>>>(buf_h, W2, b2, buf_s, N);
    agg_gn_kernel<<<aggBlocks, BLK, 0, stream>>>(buf_s, rowptr, colidx, wv, g2, beta2, buf_h, N);

    // ---- layer 3: out = log_softmax(gcn(h, W3, b3)) ----
    lin_kernel<64, 40><<<grid((long)N * 10, BLK), BLK, 0, stream>>>(buf_h, W3, b3, buf_s, N);
    agg_lsm_kernel<<<aggBlocks, BLK, 0, stream>>>(buf_s, rowptr, colidx, wv, (float*)d_out, N);
}

// Round 3
// 438.793 us; speedup vs baseline: 2.3072x; 1.3180x over previous
//
#include <hip/hip_runtime.h>
#include <hip/hip_bf16.h>
#include <math.h>

// ---------------------------------------------------------------------------
// RESKnorm GCN, CSR-based (no float atomics):
//   per call: build CSR of edges grouped by tgt (histogram + 3-phase
//   device-wide scan + fill), then per layer: S = X@W+b (lin), then
//   one-wave-per-node aggregation with fused epilogue
//   (relu / relu+GN+residual / log_softmax).
// N=50000, E=800000, NFEAT=128, NHID=64, NCLASS=40, GROUPS=32 (2 ch/group)
// ---------------------------------------------------------------------------

#define EPS 1e-5f
#define SCAN_BLK 256

// ---------------- CSR build ----------------
__global__ void count_kernel(const int* __restrict__ tgt, int* __restrict__ cnt,
                             int E) {
    int e = blockIdx.x * blockDim.x + threadIdx.x;
    if (e < E) atomicAdd(&cnt[tgt[e]], 1);
}

// phase 1: per-block sums of cnt
__global__ void scan_p1(const int* __restrict__ cnt, int* __restrict__ bsum,
                        int n) {
    __shared__ int lds[SCAN_BLK];
    int i = blockIdx.x * SCAN_BLK + threadIdx.x;
    lds[threadIdx.x] = (i < n) ? cnt[i] : 0;
    __syncthreads();
    for (int off = SCAN_BLK / 2; off; off >>= 1) {
        if (threadIdx.x < off) lds[threadIdx.x] += lds[threadIdx.x + off];
        __syncthreads();
    }
    if (threadIdx.x == 0) bsum[blockIdx.x] = lds[0];
}

// phase 2: single small block, exclusive scan of block sums (nblocks <= 1024)
__global__ void scan_p2(int* __restrict__ bsum, int nblocks) {
    __shared__ int lds[1024];
    int tid = threadIdx.x;
    int v = (tid < nblocks) ? bsum[tid] : 0;
    lds[tid] = v;
    __syncthreads();
    for (int off = 1; off < 1024; off <<= 1) {
        int t = (tid >= off) ? lds[tid - off] : 0;
        __syncthreads();
        lds[tid] += t;
        __syncthreads();
    }
    if (tid < nblocks) bsum[tid] = lds[tid] - v;  // exclusive
}

// phase 3: per-block inclusive scan + block offset -> rowptr/cursor
__global__ void scan_p3(const int* __restrict__ cnt, const int* __restrict__ bsum,
                        int* __restrict__ rowptr, int* __restrict__ cursor,
                        int n) {
    __shared__ int lds[SCAN_BLK];
    int i = blockIdx.x * SCAN_BLK + threadIdx.x;
    int v = (i < n) ? cnt[i] : 0;
    lds[threadIdx.x] = v;
    __syncthreads();
    for (int off = 1; off < SCAN_BLK; off <<= 1) {
        int t = (threadIdx.x >= off) ? lds[threadIdx.x - off] : 0;
        __syncthreads();
        lds[threadIdx.x] += t;
        __syncthreads();
    }
    int excl = bsum[blockIdx.x] + lds[threadIdx.x] - v;
    if (i < n) {
        rowptr[i] = excl;
        cursor[i] = excl;
        if (i == n - 1) rowptr[n] = excl + v;
    }
}

__global__ void fill_kernel(const int* __restrict__ src, const int* __restrict__ tgt,
                            const float* __restrict__ mv, int* __restrict__ cursor,
                            int* __restrict__ colidx, float* __restrict__ wv, int E) {
    int e = blockIdx.x * blockDim.x + threadIdx.x;
    if (e >= E) return;
    int pos = atomicAdd(&cursor[tgt[e]], 1);
    colidx[pos] = src[e];
    wv[pos] = mv[e];
}

// ---------------- S = X @ W + b ----------------
template <int K, int COLS>
__global__ void lin_kernel(const float* __restrict__ X, const float* __restrict__ W,
                           const float* __restrict__ B, float* __restrict__ S,
                           int n) {
    constexpr int C4 = COLS / 4;
    __shared__ float4 Wl[K * C4];
    __shared__ float Bl[COLS];
    for (int i = threadIdx.x; i < K * C4; i += blockDim.x)
        Wl[i] = ((const float4*)W)[i];
    for (int i = threadIdx.x; i < COLS; i += blockDim.x) Bl[i] = B[i];
    __syncthreads();
    int idx = blockIdx.x * blockDim.x + threadIdx.x;
    int total = n * C4;
    if (idx >= total) return;
    int row = idx / C4;
    int c4 = idx - row * C4;
    const float* xr = X + (long)row * K;
    float4 acc;
    acc.x = Bl[4 * c4 + 0];
    acc.y = Bl[4 * c4 + 1];
    acc.z = Bl[4 * c4 + 2];
    acc.w = Bl[4 * c4 + 3];
#pragma unroll 4
    for (int k = 0; k < K; ++k) {
        float xv = xr[k];
        float4 w = Wl[k * C4 + c4];
        acc.x = fmaf(xv, w.x, acc.x);
        acc.y = fmaf(xv, w.y, acc.y);
        acc.z = fmaf(xv, w.z, acc.z);
        acc.w = fmaf(xv, w.w, acc.w);
    }
    ((float4*)S)[idx] = acc;
}

// ---------------- aggregation: one wave per node, lane = channel ----------
// 4-deep unrolled gather loop (4 independent chains to hide gather latency)
#define AGG_BODY(F)                                                          \
    int beg = rowptr[wid], end = rowptr[wid + 1];                            \
    float acc0 = 0.f, acc1 = 0.f, acc2 = 0.f, acc3 = 0.f;                    \
    int j = beg;                                                             \
    for (; j + 3 < end; j += 4) {                                            \
        int s0 = colidx[j], s1 = colidx[j + 1];                              \
        int s2 = colidx[j + 2], s3 = colidx[j + 3];                          \
        float w0 = wv[j], w1 = wv[j + 1], w2 = wv[j + 2], w3 = wv[j + 3];    \
        acc0 = fmaf(S[(long)s0 * F + lane], w0, acc0);                       \
        acc1 = fmaf(S[(long)s1 * F + lane], w1, acc1);                       \
        acc2 = fmaf(S[(long)s2 * F + lane], w2, acc2);                       \
        acc3 = fmaf(S[(long)s3 * F + lane], w3, acc3);                       \
    }                                                                        \
    for (; j < end; ++j)                                                     \
        acc0 = fmaf(S[(long)colidx[j] * F + lane], wv[j], acc0);             \
    float accv = (acc0 + acc1) + (acc2 + acc3);

// layer 0 epilogue: relu
__global__ void agg_relu_kernel(const float* __restrict__ S,
                                const int* __restrict__ rowptr,
                                const int* __restrict__ colidx,
                                const float* __restrict__ wv,
                                float* __restrict__ H, int n) {
    int wid = (blockIdx.x * blockDim.x + threadIdx.x) >> 6;
    int lane = threadIdx.x & 63;
    if (wid >= n) return;
    AGG_BODY(64)
    H[(long)wid * 64 + lane] = fmaxf(accv, 0.f);
}

// layers 1-2 epilogue: relu + groupnorm(2ch/group, closed form) + residual
__global__ void agg_gn_kernel(const float* __restrict__ S,
                              const int* __restrict__ rowptr,
                              const int* __restrict__ colidx,
                              const float* __restrict__ wv,
                              const float* __restrict__ gamma,
                              const float* __restrict__ beta,
                              float* __restrict__ H, int n) {
    int wid = (blockIdx.x * blockDim.x + threadIdx.x) >> 6;
    int lane = threadIdx.x & 63;
    if (wid >= n) return;
    AGG_BODY(64)
    float a = fmaxf(accv, 0.f);
    float b = __shfl_xor(a, 1);       // partner channel within the 2-ch group
    float d = 0.5f * (a - b);         // a - mu ; var = d*d
    float rs = rsqrtf(d * d + EPS);
    long off = (long)wid * 64 + lane;
    H[off] = d * rs * gamma[lane] + beta[lane] + H[off];
}

// layer 3 epilogue: log_softmax over 40 classes (lanes 0..39 active)
__global__ void agg_lsm_kernel(const float* __restrict__ S,
                               const int* __restrict__ rowptr,
                               const int* __restrict__ colidx,
                               const float* __restrict__ wv,
                               float* __restrict__ out, int n) {
    int wid = (blockIdx.x * blockDim.x + threadIdx.x) >> 6;
    int lane = threadIdx.x & 63;
    if (wid >= n) return;
    int lane40 = (lane < 40) ? lane : 39;   // clamp: avoid OOB, lanes 40-63 dup
    AGG_BODY(40)
    (void)accv;
    float v = (acc0 + acc1) + (acc2 + acc3);
    bool act = lane < 40;
    float m = act ? v : -INFINITY;
#pragma unroll
    for (int off = 32; off; off >>= 1) m = fmaxf(m, __shfl_xor(m, off));
    float ex = act ? expf(v - m) : 0.f;
#pragma unroll
    for (int off = 32; off; off >>= 1) ex += __shfl_xor(ex, off);
    float l = m + logf(ex);
    if (act) out[(long)wid * 40 + lane] = v - l;
}

extern "C" void kernel_launch(void* const* d_in, const int* in_sizes, int n_in,
                              void* d_out, int out_size, void* d_ws,
                              size_t ws_size, hipStream_t stream) {
    const float* x = (const float*)d_in[0];
    const int* src = (const int*)d_in[1];
    const int* tgt = (const int*)d_in[2];
    const float* mv = (const float*)d_in[3];
    const float* W0 = (const float*)d_in[4];
    const float* b0 = (const float*)d_in[5];
    const float* W1 = (const float*)d_in[6];
    const float* b1 = (const float*)d_in[7];
    const float* W2 = (const float*)d_in[8];
    const float* b2 = (const float*)d_in[9];
    const float* W3 = (const float*)d_in[10];
    const float* b3 = (const float*)d_in[11];
    const float* g1 = (const float*)d_in[12];
    const float* beta1 = (const float*)d_in[13];
    const float* g2 = (const float*)d_in[14];
    const float* beta2 = (const float*)d_in[15];

    const int N = in_sizes[0] / 128;
    const int E = in_sizes[1];

    float* buf_s = (float*)d_ws;               // [N,64] linear output
    float* buf_h = buf_s + (size_t)N * 64;     // [N,64] h / residual (in-place)
    int* rowptr = (int*)(buf_h + (size_t)N * 64);  // [N+1]
    int* cursor = rowptr + (N + 1);            // [N]
    int* cnt = cursor + N;                     // [N]
    int* bsum = cnt + N;                       // [<=1024]
    int* colidx = bsum + 1024;                 // [E]
    float* wv = (float*)(colidx + E);          // [E]

    const int BLK = 256;
    auto grid = [](long total, int blk) { return (int)((total + blk - 1) / blk); };
    const int scanBlocks = grid(N, SCAN_BLK);

    // ---- CSR build (once per call; reused by all 4 layers) ----
    hipMemsetAsync(cnt, 0, (size_t)N * sizeof(int), stream);
    count_kernel<<<grid(E, BLK), BLK, 0, stream>>>(tgt, cnt, E);
    scan_p1<<<scanBlocks, SCAN_BLK, 0, stream>>>(cnt, bsum, N);
    scan_p2<<<1, 1024, 0, stream>>>(bsum, scanBlocks);
    scan_p3<<<scanBlocks, SCAN_BLK, 0, stream>>>(cnt, bsum, rowptr, cursor, N);
    fill_kernel<<<grid(E, BLK), BLK, 0, stream>>>(src, tgt, mv, cursor, colidx, wv, E);

    const int aggBlocks = grid((long)N * 64, BLK);  // 4 waves (nodes) per block

    // ---- layer 0: h = relu(gcn(x, W0, b0)) ----
    lin_kernel<128, 64><<<grid((long)N * 16, BLK), BLK, 0, stream>>>(x, W0, b0, buf_s, N);
    agg_relu_kernel<<<aggBlocks, BLK, 0, stream>>>(buf_s, rowptr, colidx, wv, buf_h, N);

    // ---- layer 1 ----
    lin_kernel<64, 64><<<grid((long)N * 16, BLK), BLK, 0, stream>>>(buf_h, W1, b1, buf_s, N);
    agg_gn_kernel<<<aggBlocks, BLK, 0, stream>>>(buf_s, rowptr, colidx, wv, g1, beta1, buf_h, N);

    // ---- layer 2 ----
    lin_kernel<64, 64><<<grid((long)N * 16, BLK), BLK, 0, stream>>>(buf_h, W2, b2, buf_s, N);
    agg_gn_kernel<<<aggBlocks, BLK, 0, stream>>>(buf_s, rowptr, colidx, wv, g2, beta2, buf_h, N);

    // ---- layer 3: out = log_softmax(gcn(h, W3, b3)) ----
    lin_kernel<64, 40><<<grid((long)N * 10, BLK), BLK, 0, stream>>>(buf_h, W3, b3, buf_s, N);
    agg_lsm_kernel<<<aggBlocks, BLK, 0, stream>>>(buf_s, rowptr, colidx, wv, (float*)d_out, N);
}

// Round 5
// 430.148 us; speedup vs baseline: 2.3535x; 1.0201x over previous
//
#include <hip/hip_runtime.h>
#include <hip/hip_bf16.h>
#include <math.h>

// ---------------------------------------------------------------------------
// RESKnorm GCN, CSR-based (no float atomics), f32 message matrix:
//   CSR build: histogram + 3-phase device-wide scan + fill with PACKED int2
//   edge payload {src, float_bits(Mtgt)} -> one 8B scatter per edge.
//   Per layer: S = X@W+b (lin), then one-wave-per-node aggregation with fused
//   epilogue (relu / relu+GN+residual / log_softmax). All f32 (bf16 S failed
//   accuracy in R4: absmax 2.719 > 2.64).
// N=50000, E=800000, NFEAT=128, NHID=64, NCLASS=40, GROUPS=32 (2 ch/group)
// ---------------------------------------------------------------------------

#define EPS 1e-5f
#define SCAN_BLK 256

// ---------------- CSR build ----------------
__global__ void count_kernel(const int* __restrict__ tgt, int* __restrict__ cnt,
                             int E) {
    int e = blockIdx.x * blockDim.x + threadIdx.x;
    if (e < E) atomicAdd(&cnt[tgt[e]], 1);
}

__global__ void scan_p1(const int* __restrict__ cnt, int* __restrict__ bsum,
                        int n) {
    __shared__ int lds[SCAN_BLK];
    int i = blockIdx.x * SCAN_BLK + threadIdx.x;
    lds[threadIdx.x] = (i < n) ? cnt[i] : 0;
    __syncthreads();
    for (int off = SCAN_BLK / 2; off; off >>= 1) {
        if (threadIdx.x < off) lds[threadIdx.x] += lds[threadIdx.x + off];
        __syncthreads();
    }
    if (threadIdx.x == 0) bsum[blockIdx.x] = lds[0];
}

__global__ void scan_p2(int* __restrict__ bsum, int nblocks) {
    __shared__ int lds[1024];
    int tid = threadIdx.x;
    int v = (tid < nblocks) ? bsum[tid] : 0;
    lds[tid] = v;
    __syncthreads();
    for (int off = 1; off < 1024; off <<= 1) {
        int t = (tid >= off) ? lds[tid - off] : 0;
        __syncthreads();
        lds[tid] += t;
        __syncthreads();
    }
    if (tid < nblocks) bsum[tid] = lds[tid] - v;  // exclusive
}

__global__ void scan_p3(const int* __restrict__ cnt, const int* __restrict__ bsum,
                        int* __restrict__ rowptr, int* __restrict__ cursor,
                        int n) {
    __shared__ int lds[SCAN_BLK];
    int i = blockIdx.x * SCAN_BLK + threadIdx.x;
    int v = (i < n) ? cnt[i] : 0;
    lds[threadIdx.x] = v;
    __syncthreads();
    for (int off = 1; off < SCAN_BLK; off <<= 1) {
        int t = (threadIdx.x >= off) ? lds[threadIdx.x - off] : 0;
        __syncthreads();
        lds[threadIdx.x] += t;
        __syncthreads();
    }
    int excl = bsum[blockIdx.x] + lds[threadIdx.x] - v;
    if (i < n) {
        rowptr[i] = excl;
        cursor[i] = excl;
        if (i == n - 1) rowptr[n] = excl + v;
    }
}

// packed edge: .x = src index, .y = float bits of Mtgt; ONE 8B scatter/edge
__global__ void fill_kernel(const int* __restrict__ src, const int* __restrict__ tgt,
                            const float* __restrict__ mv, int* __restrict__ cursor,
                            int2* __restrict__ ep, int E) {
    int e = blockIdx.x * blockDim.x + threadIdx.x;
    if (e >= E) return;
    int pos = atomicAdd(&cursor[tgt[e]], 1);
    int2 v;
    v.x = src[e];
    v.y = __float_as_int(mv[e]);
    ep[pos] = v;
}

// ---------------- S = X @ W + b ----------------
template <int K, int COLS>
__global__ void lin_kernel(const float* __restrict__ X, const float* __restrict__ W,
                           const float* __restrict__ B, float* __restrict__ S,
                           int n) {
    constexpr int C4 = COLS / 4;
    __shared__ float4 Wl[K * C4];
    __shared__ float Bl[COLS];
    for (int i = threadIdx.x; i < K * C4; i += blockDim.x)
        Wl[i] = ((const float4*)W)[i];
    for (int i = threadIdx.x; i < COLS; i += blockDim.x) Bl[i] = B[i];
    __syncthreads();
    int idx = blockIdx.x * blockDim.x + threadIdx.x;
    int total = n * C4;
    if (idx >= total) return;
    int row = idx / C4;
    int c4 = idx - row * C4;
    const float* xr = X + (long)row * K;
    float4 acc;
    acc.x = Bl[4 * c4 + 0];
    acc.y = Bl[4 * c4 + 1];
    acc.z = Bl[4 * c4 + 2];
    acc.w = Bl[4 * c4 + 3];
#pragma unroll 4
    for (int k = 0; k < K; ++k) {
        float xv = xr[k];
        float4 w = Wl[k * C4 + c4];
        acc.x = fmaf(xv, w.x, acc.x);
        acc.y = fmaf(xv, w.y, acc.y);
        acc.z = fmaf(xv, w.z, acc.z);
        acc.w = fmaf(xv, w.w, acc.w);
    }
    ((float4*)S)[idx] = acc;
}

// ---------------- aggregation: one wave per node, lane = channel ----------
// 4-deep unrolled gather loop; edge payload is one uniform 8B load/edge
#define AGG_BODY(F, LL)                                                       \
    int beg = rowptr[wid], end = rowptr[wid + 1];                             \
    float acc0 = 0.f, acc1 = 0.f, acc2 = 0.f, acc3 = 0.f;                     \
    int j = beg;                                                              \
    for (; j + 3 < end; j += 4) {                                             \
        int2 e0 = ep[j], e1 = ep[j + 1], e2 = ep[j + 2], e3 = ep[j + 3];      \
        float v0 = S[(long)e0.x * F + LL];                                    \
        float v1 = S[(long)e1.x * F + LL];                                    \
        float v2 = S[(long)e2.x * F + LL];                                    \
        float v3 = S[(long)e3.x * F + LL];                                    \
        acc0 = fmaf(v0, __int_as_float(e0.y), acc0);                          \
        acc1 = fmaf(v1, __int_as_float(e1.y), acc1);                          \
        acc2 = fmaf(v2, __int_as_float(e2.y), acc2);                          \
        acc3 = fmaf(v3, __int_as_float(e3.y), acc3);                          \
    }                                                                         \
    for (; j < end; ++j) {                                                    \
        int2 e0 = ep[j];                                                      \
        acc0 = fmaf(S[(long)e0.x * F + LL], __int_as_float(e0.y), acc0);      \
    }                                                                         \
    float accv = (acc0 + acc1) + (acc2 + acc3);

// layer 0 epilogue: relu
__global__ void agg_relu_kernel(const float* __restrict__ S,
                                const int* __restrict__ rowptr,
                                const int2* __restrict__ ep,
                                float* __restrict__ H, int n) {
    int wid = (blockIdx.x * blockDim.x + threadIdx.x) >> 6;
    int lane = threadIdx.x & 63;
    if (wid >= n) return;
    AGG_BODY(64, lane)
    H[(long)wid * 64 + lane] = fmaxf(accv, 0.f);
}

// layers 1-2: relu + groupnorm (2ch/group closed form via shuffle) + residual
__global__ void agg_gn_kernel(const float* __restrict__ S,
                              const int* __restrict__ rowptr,
                              const int2* __restrict__ ep,
                              const float* __restrict__ gamma,
                              const float* __restrict__ beta,
                              float* __restrict__ H, int n) {
    int wid = (blockIdx.x * blockDim.x + threadIdx.x) >> 6;
    int lane = threadIdx.x & 63;
    if (wid >= n) return;
    AGG_BODY(64, lane)
    float a = fmaxf(accv, 0.f);
    float b = __shfl_xor(a, 1);       // partner channel within the 2-ch group
    float d = 0.5f * (a - b);         // a - mu ; var = d*d
    float rs = rsqrtf(d * d + EPS);
    long off = (long)wid * 64 + lane;
    H[off] = d * rs * gamma[lane] + beta[lane] + H[off];
}

// layer 3: log_softmax over 40 classes (lanes 0..39 active)
__global__ void agg_lsm_kernel(const float* __restrict__ S,
                               const int* __restrict__ rowptr,
                               const int2* __restrict__ ep,
                               float* __restrict__ out, int n) {
    int wid = (blockIdx.x * blockDim.x + threadIdx.x) >> 6;
    int lane = threadIdx.x & 63;
    if (wid >= n) return;
    int ll = (lane < 40) ? lane : 39;   // clamp: in-bounds dup loads, inactive
    AGG_BODY(40, ll)
    float v = accv;
    bool act = lane < 40;
    float m = act ? v : -INFINITY;
#pragma unroll
    for (int off = 32; off; off >>= 1) m = fmaxf(m, __shfl_xor(m, off));
    float ex = act ? expf(v - m) : 0.f;
#pragma unroll
    for (int off = 32; off; off >>= 1) ex += __shfl_xor(ex, off);
    float l = m + logf(ex);
    if (act) out[(long)wid * 40 + lane] = v - l;
}

extern "C" void kernel_launch(void* const* d_in, const int* in_sizes, int n_in,
                              void* d_out, int out_size, void* d_ws,
                              size_t ws_size, hipStream_t stream) {
    const float* x = (const float*)d_in[0];
    const int* src = (const int*)d_in[1];
    const int* tgt = (const int*)d_in[2];
    const float* mv = (const float*)d_in[3];
    const float* W0 = (const float*)d_in[4];
    const float* b0 = (const float*)d_in[5];
    const float* W1 = (const float*)d_in[6];
    const float* b1 = (const float*)d_in[7];
    const float* W2 = (const float*)d_in[8];
    const float* b2 = (const float*)d_in[9];
    const float* W3 = (const float*)d_in[10];
    const float* b3 = (const float*)d_in[11];
    const float* g1 = (const float*)d_in[12];
    const float* beta1 = (const float*)d_in[13];
    const float* g2 = (const float*)d_in[14];
    const float* beta2 = (const float*)d_in[15];

    const int N = in_sizes[0] / 128;
    const int E = in_sizes[1];

    float* buf_s = (float*)d_ws;               // [N,64] linear output (f32)
    float* buf_h = buf_s + (size_t)N * 64;     // [N,64] h / residual (in-place)
    int* rowptr = (int*)(buf_h + (size_t)N * 64);  // [N+1]
    int* cursor = rowptr + (N + 1);            // [N]
    int* cnt = cursor + N;                     // [N]
    int* bsum = cnt + N;                       // [<=1024]
    int2* epack = (int2*)(((uintptr_t)(bsum + 1024) + 15) & ~(uintptr_t)15);  // [E]

    const int BLK = 256;
    auto grid = [](long total, int blk) { return (int)((total + blk - 1) / blk); };
    const int scanBlocks = grid(N, SCAN_BLK);

    // ---- CSR build (once per call; reused by all 4 layers) ----
    hipMemsetAsync(cnt, 0, (size_t)N * sizeof(int), stream);
    count_kernel<<<grid(E, BLK), BLK, 0, stream>>>(tgt, cnt, E);
    scan_p1<<<scanBlocks, SCAN_BLK, 0, stream>>>(cnt, bsum, N);
    scan_p2<<<1, 1024, 0, stream>>>(bsum, scanBlocks);
    scan_p3<<<scanBlocks, SCAN_BLK, 0, stream>>>(cnt, bsum, rowptr, cursor, N);
    fill_kernel<<<grid(E, BLK), BLK, 0, stream>>>(src, tgt, mv, cursor, epack, E);

    const int aggBlocks = grid((long)N * 64, BLK);  // 4 waves (nodes) per block

    // ---- layer 0: h = relu(gcn(x, W0, b0)) ----
    lin_kernel<128, 64><<<grid((long)N * 16, BLK), BLK, 0, stream>>>(x, W0, b0, buf_s, N);
    agg_relu_kernel<<<aggBlocks, BLK, 0, stream>>>(buf_s, rowptr, epack, buf_h, N);

    // ---- layer 1 ----
    lin_kernel<64, 64><<<grid((long)N * 16, BLK), BLK, 0, stream>>>(buf_h, W1, b1, buf_s, N);
    agg_gn_kernel<<<aggBlocks, BLK, 0, stream>>>(buf_s, rowptr, epack, g1, beta1, buf_h, N);

    // ---- layer 2 ----
    lin_kernel<64, 64><<<grid((long)N * 16, BLK), BLK, 0, stream>>>(buf_h, W2, b2, buf_s, N);
    agg_gn_kernel<<<aggBlocks, BLK, 0, stream>>>(buf_s, rowptr, epack, g2, beta2, buf_h, N);

    // ---- layer 3: out = log_softmax(gcn(h, W3, b3)) ----
    lin_kernel<64, 40><<<grid((long)N * 10, BLK), BLK, 0, stream>>>(buf_h, W3, b3, buf_s, N);
    agg_lsm_kernel<<<aggBlocks, BLK, 0, stream>>>(buf_s, rowptr, epack, (float*)d_out, N);
}

// Round 6
// 399.555 us; speedup vs baseline: 2.5337x; 1.0766x over previous
//
#include <hip/hip_runtime.h>
#include <hip/hip_bf16.h>
#include <math.h>

// ---------------------------------------------------------------------------
// RESKnorm GCN, CSR-based (no float atomics), f32 message matrix:
//   CSR build: histogram + 3-phase scan + fill (packed 8B {src,w} NT store).
//   Per layer: S = X@W+b (lin), then QUARTER-WAVE aggregation: each 16-lane
//   quarter processes a different edge, lanes load float4 of the source row;
//   cross-quarter shuffle-reduce; fused epilogue (relu / relu+GN+residual /
//   log_softmax). GN pair (2i,2i+1) is lane-local in the float4.
// N=50000, E=800000, NFEAT=128, NHID=64, NCLASS=40, GROUPS=32 (2 ch/group)
// ---------------------------------------------------------------------------

#define EPS 1e-5f
#define SCAN_BLK 256

// ---------------- CSR build ----------------
__global__ void count_kernel(const int* __restrict__ tgt, int* __restrict__ cnt,
                             int E) {
    int e = blockIdx.x * blockDim.x + threadIdx.x;
    if (e < E) atomicAdd(&cnt[tgt[e]], 1);
}

__global__ void scan_p1(const int* __restrict__ cnt, int* __restrict__ bsum,
                        int n) {
    __shared__ int lds[SCAN_BLK];
    int i = blockIdx.x * SCAN_BLK + threadIdx.x;
    lds[threadIdx.x] = (i < n) ? cnt[i] : 0;
    __syncthreads();
    for (int off = SCAN_BLK / 2; off; off >>= 1) {
        if (threadIdx.x < off) lds[threadIdx.x] += lds[threadIdx.x + off];
        __syncthreads();
    }
    if (threadIdx.x == 0) bsum[blockIdx.x] = lds[0];
}

__global__ void scan_p2(int* __restrict__ bsum, int nblocks) {
    __shared__ int lds[1024];
    int tid = threadIdx.x;
    int v = (tid < nblocks) ? bsum[tid] : 0;
    lds[tid] = v;
    __syncthreads();
    for (int off = 1; off < 1024; off <<= 1) {
        int t = (tid >= off) ? lds[tid - off] : 0;
        __syncthreads();
        lds[tid] += t;
        __syncthreads();
    }
    if (tid < nblocks) bsum[tid] = lds[tid] - v;  // exclusive
}

__global__ void scan_p3(const int* __restrict__ cnt, const int* __restrict__ bsum,
                        int* __restrict__ rowptr, int* __restrict__ cursor,
                        int n) {
    __shared__ int lds[SCAN_BLK];
    int i = blockIdx.x * SCAN_BLK + threadIdx.x;
    int v = (i < n) ? cnt[i] : 0;
    lds[threadIdx.x] = v;
    __syncthreads();
    for (int off = 1; off < SCAN_BLK; off <<= 1) {
        int t = (threadIdx.x >= off) ? lds[threadIdx.x - off] : 0;
        __syncthreads();
        lds[threadIdx.x] += t;
        __syncthreads();
    }
    int excl = bsum[blockIdx.x] + lds[threadIdx.x] - v;
    if (i < n) {
        rowptr[i] = excl;
        cursor[i] = excl;
        if (i == n - 1) rowptr[n] = excl + v;
    }
}

// packed edge {src, float_bits(Mtgt)}: ONE 8B non-temporal scatter per edge
__global__ void fill_kernel(const int* __restrict__ src, const int* __restrict__ tgt,
                            const float* __restrict__ mv, int* __restrict__ cursor,
                            long long* __restrict__ ep, int E) {
    int e = blockIdx.x * blockDim.x + threadIdx.x;
    if (e >= E) return;
    int pos = atomicAdd(&cursor[tgt[e]], 1);
    long long v = (long long)(unsigned)src[e] |
                  ((long long)__float_as_int(mv[e]) << 32);
    __builtin_nontemporal_store(v, &ep[pos]);
}

// ---------------- S = X @ W + b ----------------
template <int K, int COLS>
__global__ void lin_kernel(const float* __restrict__ X, const float* __restrict__ W,
                           const float* __restrict__ B, float* __restrict__ S,
                           int n) {
    constexpr int C4 = COLS / 4;
    __shared__ float4 Wl[K * C4];
    __shared__ float Bl[COLS];
    for (int i = threadIdx.x; i < K * C4; i += blockDim.x)
        Wl[i] = ((const float4*)W)[i];
    for (int i = threadIdx.x; i < COLS; i += blockDim.x) Bl[i] = B[i];
    __syncthreads();
    int idx = blockIdx.x * blockDim.x + threadIdx.x;
    int total = n * C4;
    if (idx >= total) return;
    int row = idx / C4;
    int c4 = idx - row * C4;
    const float* xr = X + (long)row * K;
    float4 acc;
    acc.x = Bl[4 * c4 + 0];
    acc.y = Bl[4 * c4 + 1];
    acc.z = Bl[4 * c4 + 2];
    acc.w = Bl[4 * c4 + 3];
#pragma unroll 4
    for (int k = 0; k < K; ++k) {
        float xv = xr[k];
        float4 w = Wl[k * C4 + c4];
        acc.x = fmaf(xv, w.x, acc.x);
        acc.y = fmaf(xv, w.y, acc.y);
        acc.z = fmaf(xv, w.z, acc.z);
        acc.w = fmaf(xv, w.w, acc.w);
    }
    ((float4*)S)[idx] = acc;
}

// ---------------- quarter-wave aggregation ----------------
// wave = 1 node; quarter q processes edge j+q; lane loads float4 (16B) of row.
// R4 = row stride in float4 units. Valid-channel predicate VALIDSUB.
// After the loop: cross-quarter reduce so all lanes hold the channel-block sum.
#define AGG4_BODY(R4)                                                         \
    int beg = rowptr[wid], end = rowptr[wid + 1];                             \
    float4 acc = make_float4(0.f, 0.f, 0.f, 0.f);                             \
    float4 acc2 = make_float4(0.f, 0.f, 0.f, 0.f);                            \
    int j = beg;                                                              \
    for (; j + 8 <= end; j += 8) {                                            \
        long long p0 = ep[j + q];                                             \
        long long p1 = ep[j + 4 + q];                                         \
        int s0 = (int)(unsigned)p0;                                           \
        int s1 = (int)(unsigned)p1;                                           \
        float w0 = __int_as_float((int)(p0 >> 32));                           \
        float w1 = __int_as_float((int)(p1 >> 32));                           \
        float4 v0 = S4[(long)s0 * R4 + sub];                                  \
        float4 v1 = S4[(long)s1 * R4 + sub];                                  \
        acc.x = fmaf(v0.x, w0, acc.x); acc.y = fmaf(v0.y, w0, acc.y);         \
        acc.z = fmaf(v0.z, w0, acc.z); acc.w = fmaf(v0.w, w0, acc.w);         \
        acc2.x = fmaf(v1.x, w1, acc2.x); acc2.y = fmaf(v1.y, w1, acc2.y);     \
        acc2.z = fmaf(v1.z, w1, acc2.z); acc2.w = fmaf(v1.w, w1, acc2.w);     \
    }                                                                         \
    for (; j < end; j += 4) {                                                 \
        int eidx = j + q;                                                     \
        long long p0 = ep[(eidx < end) ? eidx : (end - 1)];                   \
        int s0 = (int)(unsigned)p0;                                           \
        float w0 = (eidx < end) ? __int_as_float((int)(p0 >> 32)) : 0.f;      \
        float4 v0 = S4[(long)s0 * R4 + sub];                                  \
        acc.x = fmaf(v0.x, w0, acc.x); acc.y = fmaf(v0.y, w0, acc.y);         \
        acc.z = fmaf(v0.z, w0, acc.z); acc.w = fmaf(v0.w, w0, acc.w);         \
    }                                                                         \
    acc.x += acc2.x; acc.y += acc2.y; acc.z += acc2.z; acc.w += acc2.w;       \
    acc.x += __shfl_xor(acc.x, 16); acc.y += __shfl_xor(acc.y, 16);           \
    acc.z += __shfl_xor(acc.z, 16); acc.w += __shfl_xor(acc.w, 16);           \
    acc.x += __shfl_xor(acc.x, 32); acc.y += __shfl_xor(acc.y, 32);           \
    acc.z += __shfl_xor(acc.z, 32); acc.w += __shfl_xor(acc.w, 32);

// layer 0 epilogue: relu
__global__ void agg_relu_kernel(const float4* __restrict__ S4,
                                const int* __restrict__ rowptr,
                                const long long* __restrict__ ep,
                                float4* __restrict__ H4, int n) {
    int wid = (blockIdx.x * blockDim.x + threadIdx.x) >> 6;
    int lane = threadIdx.x & 63;
    int q = lane >> 4, sub = lane & 15;
    if (wid >= n) return;
    AGG4_BODY(16)
    if (q != 0) return;
    H4[(long)wid * 16 + sub] = make_float4(fmaxf(acc.x, 0.f), fmaxf(acc.y, 0.f),
                                           fmaxf(acc.z, 0.f), fmaxf(acc.w, 0.f));
}

// layers 1-2: relu + groupnorm (pairs (x,y),(z,w) lane-local) + residual
__global__ void agg_gn_kernel(const float4* __restrict__ S4,
                              const int* __restrict__ rowptr,
                              const long long* __restrict__ ep,
                              const float4* __restrict__ gamma,
                              const float4* __restrict__ beta,
                              float4* __restrict__ H4, int n) {
    int wid = (blockIdx.x * blockDim.x + threadIdx.x) >> 6;
    int lane = threadIdx.x & 63;
    int q = lane >> 4, sub = lane & 15;
    if (wid >= n) return;
    AGG4_BODY(16)
    if (q != 0) return;
    float a0 = fmaxf(acc.x, 0.f), a1 = fmaxf(acc.y, 0.f);
    float a2 = fmaxf(acc.z, 0.f), a3 = fmaxf(acc.w, 0.f);
    float dA = 0.5f * (a0 - a1);
    float dB = 0.5f * (a2 - a3);
    float rsA = rsqrtf(dA * dA + EPS);
    float rsB = rsqrtf(dB * dB + EPS);
    float4 g = gamma[sub], be = beta[sub];
    long off = (long)wid * 16 + sub;
    float4 h = H4[off];
    h.x += dA * rsA * g.x + be.x;
    h.y += -dA * rsA * g.y + be.y;
    h.z += dB * rsB * g.z + be.z;
    h.w += -dB * rsB * g.w + be.w;
    H4[off] = h;
}

// layer 3: log_softmax over 40 classes (10 float4 per row; sub<10 valid)
__global__ void agg_lsm_kernel(const float4* __restrict__ S4,
                               const int* __restrict__ rowptr,
                               const long long* __restrict__ ep,
                               float4* __restrict__ out4, int n) {
    int wid = (blockIdx.x * blockDim.x + threadIdx.x) >> 6;
    int lane = threadIdx.x & 63;
    int q = lane >> 4;
    int sub0 = lane & 15;
    int sub = (sub0 < 10) ? sub0 : 9;  // clamp: in-bounds dup loads, ignored
    if (wid >= n) return;
    AGG4_BODY(10)
    bool valid = sub0 < 10;
    float m = valid ? fmaxf(fmaxf(acc.x, acc.y), fmaxf(acc.z, acc.w)) : -INFINITY;
#pragma unroll
    for (int mk = 8; mk; mk >>= 1) m = fmaxf(m, __shfl_xor(m, mk));
    float ex = valid ? (expf(acc.x - m) + expf(acc.y - m) +
                        expf(acc.z - m) + expf(acc.w - m)) : 0.f;
#pragma unroll
    for (int mk = 8; mk; mk >>= 1) ex += __shfl_xor(ex, mk);
    float l = m + logf(ex);
    if (q == 0 && valid)
        out4[(long)wid * 10 + sub0] =
            make_float4(acc.x - l, acc.y - l, acc.z - l, acc.w - l);
}

extern "C" void kernel_launch(void* const* d_in, const int* in_sizes, int n_in,
                              void* d_out, int out_size, void* d_ws,
                              size_t ws_size, hipStream_t stream) {
    const float* x = (const float*)d_in[0];
    const int* src = (const int*)d_in[1];
    const int* tgt = (const int*)d_in[2];
    const float* mv = (const float*)d_in[3];
    const float* W0 = (const float*)d_in[4];
    const float* b0 = (const float*)d_in[5];
    const float* W1 = (const float*)d_in[6];
    const float* b1 = (const float*)d_in[7];
    const float* W2 = (const float*)d_in[8];
    const float* b2 = (const float*)d_in[9];
    const float* W3 = (const float*)d_in[10];
    const float* b3 = (const float*)d_in[11];
    const float* g1 = (const float*)d_in[12];
    const float* beta1 = (const float*)d_in[13];
    const float* g2 = (const float*)d_in[14];
    const float* beta2 = (const float*)d_in[15];

    const int N = in_sizes[0] / 128;
    const int E = in_sizes[1];

    float* buf_s = (float*)d_ws;               // [N,64] linear output (f32)
    float* buf_h = buf_s + (size_t)N * 64;     // [N,64] h / residual (in-place)
    int* rowptr = (int*)(buf_h + (size_t)N * 64);  // [N+1]
    int* cursor = rowptr + (N + 1);            // [N]
    int* cnt = cursor + N;                     // [N]
    int* bsum = cnt + N;                       // [<=1024]
    long long* epack = (long long*)(((uintptr_t)(bsum + 1024) + 15) & ~(uintptr_t)15);

    const int BLK = 256;
    auto grid = [](long total, int blk) { return (int)((total + blk - 1) / blk); };
    const int scanBlocks = grid(N, SCAN_BLK);

    // ---- CSR build (once per call; reused by all 4 layers) ----
    hipMemsetAsync(cnt, 0, (size_t)N * sizeof(int), stream);
    count_kernel<<<grid(E, BLK), BLK, 0, stream>>>(tgt, cnt, E);
    scan_p1<<<scanBlocks, SCAN_BLK, 0, stream>>>(cnt, bsum, N);
    scan_p2<<<1, 1024, 0, stream>>>(bsum, scanBlocks);
    scan_p3<<<scanBlocks, SCAN_BLK, 0, stream>>>(cnt, bsum, rowptr, cursor, N);
    fill_kernel<<<grid(E, BLK), BLK, 0, stream>>>(src, tgt, mv, cursor, epack, E);

    const int aggBlocks = grid((long)N * 64, BLK);  // 4 waves (nodes) per block

    // ---- layer 0: h = relu(gcn(x, W0, b0)) ----
    lin_kernel<128, 64><<<grid((long)N * 16, BLK), BLK, 0, stream>>>(x, W0, b0, buf_s, N);
    agg_relu_kernel<<<aggBlocks, BLK, 0, stream>>>((const float4*)buf_s, rowptr, epack,
                                                   (float4*)buf_h, N);

    // ---- layer 1 ----
    lin_kernel<64, 64><<<grid((long)N * 16, BLK), BLK, 0, stream>>>(buf_h, W1, b1, buf_s, N);
    agg_gn_kernel<<<aggBlocks, BLK, 0, stream>>>((const float4*)buf_s, rowptr, epack,
                                                 (const float4*)g1, (const float4*)beta1,
                                                 (float4*)buf_h, N);

    // ---- layer 2 ----
    lin_kernel<64, 64><<<grid((long)N * 16, BLK), BLK, 0, stream>>>(buf_h, W2, b2, buf_s, N);
    agg_gn_kernel<<<aggBlocks, BLK, 0, stream>>>((const float4*)buf_s, rowptr, epack,
                                                 (const float4*)g2, (const float4*)beta2,
                                                 (float4*)buf_h, N);

    // ---- layer 3: out = log_softmax(gcn(h, W3, b3)) ----
    lin_kernel<64, 40><<<grid((long)N * 10, BLK), BLK, 0, stream>>>(buf_h, W3, b3, buf_s, N);
    agg_lsm_kernel<<<aggBlocks, BLK, 0, stream>>>((const float4*)buf_s, rowptr, epack,
                                                  (float4*)d_out, N);
}